// Round 9
// baseline (222.518 us; speedup 1.0000x reference)
//
#include <hip/hip_runtime.h>

// Geometry: M=N=128, padded S=256. Two volumes (b*d=2).
// A: [v][z<128][y:256][x:256] complex fp32 = 134 MB total.
// B (packed): [v][z<128][y:256][x<128] complex fp32 = 67 MB total.
static constexpr size_t VS   = 8388608;  // 128*256*256 per volume (A)
static constexpr int    ZSTR = 65536;    // 256*256
static constexpr int    YSTR = 256;
static constexpr size_t VSB  = 4194304;  // 128*256*128 per volume (B)
static constexpr int    BZS  = 32768;    // 256*128
static constexpr int    BYS  = 128;
static constexpr int    LSTR = 261;      // LDS line stride (vf2); 5*l mod 16 spreads bank-pairs

typedef float vf2 __attribute__((ext_vector_type(2)));  // complex: .x=re, .y=im -> v_pk_* f32

__device__ __forceinline__ vf2 cmul(vf2 a, vf2 b){
    vf2 asw; asw.x = -a.y; asw.y = a.x;       // i*a
    return a*b.x + asw*b.y;                   // pk_mul + pk_fma
}

constexpr int BREV(int k){ return ((k&1)<<3)|((k&2)<<1)|((k&4)>>1)|((k&8)>>3); }

// Butterfly: a' = a+b; b' = (a-b) rotated by (c,s). Packed VOP3P.
__device__ __forceinline__ void bf(vf2& a, vf2& b, float c, float s){
    vf2 sum = a + b;
    vf2 dif = a - b;
    vf2 dsw; dsw.x = -dif.y; dsw.y = dif.x;   // i*dif
    b = dif*c + dsw*s;
    a = sum;
}

// Fully-unrolled 16-pt DIF FFT, natural input, bit-reversed output: X[k] = r[BREV(k)].
template<int DIR>
__device__ __forceinline__ void fft16(vf2 r[16]){
    constexpr float D = (float)DIR;
    constexpr float C16[8] = {1.f, 0.92387953f, 0.70710678f, 0.38268343f, 0.f, -0.38268343f, -0.70710678f, -0.92387953f};
    constexpr float S16[8] = {0.f, 0.38268343f, 0.70710678f, 0.92387953f, 1.f, 0.92387953f, 0.70710678f, 0.38268343f};
#pragma unroll
    for (int j = 0; j < 8; ++j) bf(r[j], r[j+8], C16[j], D*S16[j]);
    constexpr float C8[4] = {1.f, 0.70710678f, 0.f, -0.70710678f};
    constexpr float S8[4] = {0.f, 0.70710678f, 1.f, 0.70710678f};
#pragma unroll
    for (int g = 0; g < 16; g += 8)
#pragma unroll
        for (int j = 0; j < 4; ++j) bf(r[g+j], r[g+j+4], C8[j], D*S8[j]);
#pragma unroll
    for (int g = 0; g < 16; g += 4){
        bf(r[g],   r[g+2], 1.f, 0.f);
        bf(r[g+1], r[g+3], 0.f, D);
    }
#pragma unroll
    for (int g = 0; g < 16; g += 2) bf(r[g], r[g+1], 1.f, 0.f);
}

// Per-block twiddle table: tw[a*16+b] = e^{DIR*2pi*i*a*b/256}.
// Caller must barrier between init and first use.
__device__ __forceinline__ void init_tw(vf2* tw, float dir){
    int tid = threadIdx.x;
    float ang = dir * 0.0245436926f * (float)((tid >> 4)*(tid & 15));
    float s, c; __sincosf(ang, &s, &c);
    vf2 w; w.x = c; w.y = s;
    tw[tid] = w;
}

// Middle of four-step 256-pt FFT with an 8-LINE transpose buffer (two passes,
// low-l half then high-l half) -> halves LDS -> 8 blocks/CU.
// On entry r[n1] = x[16*n1 + t] for line l; on exit r[BREV(k2)] = X[t + 16*k2].
template<int DIR>
__device__ __forceinline__ void mid256s(vf2 r[16], vf2* sh8, const vf2* tw, int t, int l){
    fft16<DIR>(r);
#pragma unroll
    for (int k1 = 1; k1 < 16; ++k1)
        r[BREV(k1)] = cmul(r[BREV(k1)], tw[k1*16 + t]);   // broadcast across l
    int lr = l & 7;
    bool lo = (l < 8);
    __syncthreads();                      // also protects caller's prior sh8 reads
    if (lo){
#pragma unroll
        for (int k1 = 0; k1 < 16; ++k1) sh8[lr*LSTR + k1*16 + (t ^ k1)] = r[BREV(k1)];
    }
    __syncthreads();
    if (lo){
#pragma unroll
        for (int n2 = 0; n2 < 16; ++n2) r[n2] = sh8[lr*LSTR + t*16 + (n2 ^ t)];
    }
    __syncthreads();
    if (!lo){
#pragma unroll
        for (int k1 = 0; k1 < 16; ++k1) sh8[lr*LSTR + k1*16 + (t ^ k1)] = r[BREV(k1)];
    }
    __syncthreads();
    if (!lo){
#pragma unroll
        for (int n2 = 0; n2 < 16; ++n2) r[n2] = sh8[lr*LSTR + t*16 + (n2 ^ t)];
    }
    fft16<DIR>(r);
}

// Strided-axis FFT: 16 consecutive x per block, stride S elements.
// Reads only idx<NIN (rest structurally zero), writes only idx<NOUT.
template<int DIR, int NIN, int NOUT>
__device__ __forceinline__ void fft_strided(vf2* g, int S){
    __shared__ vf2 sh8[8*LSTR];
    __shared__ vf2 tw[256];
    int t = threadIdx.x >> 4, l = threadIdx.x & 15;
    vf2 r[16];
    vf2 zero; zero.x = 0.f; zero.y = 0.f;
#pragma unroll
    for (int n1 = 0; n1 < 16; ++n1)
        r[n1] = (n1 < NIN/16) ? g[(size_t)(16*n1 + t)*S + l] : zero;   // loads issue first
    init_tw(tw, (float)DIR);
    __syncthreads();                                 // tw ready
    mid256s<DIR>(r, sh8, tw, t, l);
#pragma unroll
    for (int k2 = 0; k2 < 16; ++k2)
        if (k2 < NOUT/16) g[(size_t)(t + 16*k2)*S + l] = r[BREV(k2)];
}

// P1: read input, val = sqrt(relu(f*gz^2)), zero-pad 128->256, forward FFT along x,
// then the exact half-pixel x-average epilogue (two half-passes):
//   avg[k] = 0.5*(X[k] + X[(k-1)&255]), prev tap DROPPED at k=128.
__global__ void __launch_bounds__(256) k_p1(const float* __restrict__ in, vf2* __restrict__ A){
    __shared__ vf2 sh8[8*LSTR];
    __shared__ vf2 tw[256];
    __shared__ float shin[16*130];
    init_tw(tw, -1.f);
    int th = threadIdx.x, bid = blockIdx.x;          // v*1024 + z*8 + yc
    int yc = bid & 7, z = (bid >> 3) & 127, v = bid >> 10;
    float gz = z * (1.0f/127.0f);
    float g2 = gz*gz;
    const float* src = in + (((size_t)(v*128 + z))*128 + yc*16)*128;
    for (int idx = th; idx < 2048; idx += 256){
        float val = src[idx] * g2;
        shin[(idx >> 7)*130 + (idx & 127)] = val > 0.f ? sqrtf(val) : 0.f;
    }
    __syncthreads();
    int t = th >> 4, l = th & 15;
    vf2 r[16];
    vf2 zero; zero.x = 0.f; zero.y = 0.f;
#pragma unroll
    for (int n1 = 0; n1 < 16; ++n1){
        r[n1] = zero;
        if (n1 < 8) r[n1].x = shin[l*130 + 16*n1 + t];
    }
    mid256s<-1>(r, sh8, tw, t, l);
    int lr = l & 7;
    vf2* dst = A + (size_t)v*VS + (size_t)z*ZSTR + (size_t)(yc*16)*YSTR;
#pragma unroll
    for (int half = 0; half < 2; ++half){
        __syncthreads();
        if ((l >> 3) == half){
#pragma unroll
            for (int k2 = 0; k2 < 16; ++k2) sh8[lr*LSTR + t + 16*k2] = r[BREV(k2)];
        }
        __syncthreads();
        vf2* d2 = dst + half*8*YSTR;                 // rows half*8..half*8+8 contiguous
        for (int idx = th; idx < 2048; idx += 256){
            int line = idx >> 8, k = idx & 255;
            vf2 a = sh8[line*LSTR + k];
            vf2 p = sh8[line*LSTR + ((k - 1) & 255)];
            if (k == 128) p = zero;
            d2[idx] = (a + p)*0.5f;
        }
    }
}

// P2: forward FFT along y for z<128, all x (read y<128, write 256), then the
// exact half-pixel y-average epilogue (split passes through sh8).
__global__ void __launch_bounds__(256) k_p2(vf2* __restrict__ A){
    __shared__ vf2 sh8[8*LSTR];
    __shared__ vf2 tw[256];
    int bid = blockIdx.x;                            // v*2048 + z*16 + xb
    int xb = bid & 15, z = (bid >> 4) & 127, v = bid >> 11;
    vf2* g = A + (size_t)v*VS + (size_t)z*ZSTR + xb*16;
    int t = threadIdx.x >> 4, l = threadIdx.x & 15;
    vf2 r[16];
    vf2 zero; zero.x = 0.f; zero.y = 0.f;
#pragma unroll
    for (int n1 = 0; n1 < 16; ++n1)
        r[n1] = (n1 < 8) ? g[(size_t)(16*n1 + t)*YSTR + l] : zero;
    init_tw(tw, -1.f);
    __syncthreads();
    mid256s<-1>(r, sh8, tw, t, l);
    int lr = l & 7;
#pragma unroll
    for (int half = 0; half < 2; ++half){
        __syncthreads();
        if ((l >> 3) == half){
#pragma unroll
            for (int k2 = 0; k2 < 16; ++k2) sh8[lr*LSTR + t + 16*k2] = r[BREV(k2)];
        }
        __syncthreads();
        if ((l >> 3) == half){
#pragma unroll
            for (int k2 = 0; k2 < 16; ++k2){
                int k = t + 16*k2;
                vf2 a = sh8[lr*LSTR + k];
                vf2 p = sh8[lr*LSTR + ((k - 1) & 255)];
                if (k == 128) p = zero;
                g[(size_t)k*YSTR + l] = (a + p)*0.5f;
            }
        }
    }
}

// P3: forward FFT along z for all (y,x). Read z<128, write only z<128. In-place.
__global__ void __launch_bounds__(256) k_p3(vf2* __restrict__ A){
    int bid = blockIdx.x;                            // v*4096 + y*16 + xb
    int xb = bid & 15, y = (bid >> 4) & 255, v = bid >> 12;
    fft_strided<-1,128,128>(A + (size_t)v*VS + (size_t)y*YSTR + xb*16, ZSTR);
}

// P45: fused Stolt z-resample (2 taps — x/y averaging baked into A) + x-iFFT.
// Direct global->register gather (roles t=tid&15 lane-fast for coalescing) and
// direct register->global store — no staging LDS, full load MLP.
__global__ void __launch_bounds__(256) k_p45(const vf2* __restrict__ A, vf2* __restrict__ B){
    __shared__ vf2 sh8[8*LSTR];
    __shared__ vf2 tw[256];
    init_tw(tw, 1.f);
    int tid = threadIdx.x, bid = blockIdx.x;         // v*2048 + zn*16 + yc
    int yc = bid & 15, zn = (bid >> 4) & 127, v = bid >> 11;
    const vf2* Av = A + (size_t)v*VS;
    int t = tid & 15, l = tid >> 4;                  // lanes 0..15 = consecutive x
    int yn = yc*16 + l;
    float gy = (yn < 128 ? yn : yn - 256) * (1.0f/128.0f);
    float gz = zn * (1.0f/128.0f);
    float c2 = 0.1024f*gy*gy + gz*gz;
    unsigned rowoff = (unsigned)yn*YSTR;
    vf2 r[16];
#pragma unroll
    for (int n1 = 0; n1 < 16; ++n1){
        int xn = 16*n1 + t;
        float gx = (xn < 128 ? xn : xn - 256) * (1.0f/128.0f);
        float s2 = c2 + 0.1024f*gx*gx;
        float rs = __builtin_amdgcn_rsqf(s2 + 1e-12f);   // 1/gznew; zn==0 row -> wf=0
        float gznew = s2 * rs;
        float pz = gznew*128.0f + 127.5f;
        int zi = (int)pz;                                // trunc == floor (pz>0)
        float dz = pz - (float)zi;
        int zp0 = zi - 128;                              // natural z of first tap
        float wf = gz * rs;                              // gz/gznew
        float w0 = (((unsigned)zp0     < 128u) ? (1.0f - dz) : 0.f) * wf;
        float w1 = (((unsigned)(zp0+1) < 128u) ? dz : 0.f) * wf;
        vf2 v0 = Av[(size_t)((unsigned)(zp0 & 127) * ZSTR) + rowoff + xn];
        vf2 v1 = Av[(size_t)((unsigned)((zp0 + 1) & 127) * ZSTR) + rowoff + xn];
        r[n1] = v0*w0 + v1*w1;
    }
    __syncthreads();                                 // tw ready
    mid256s<1>(r, sh8, tw, t, l);
    vf2* dst = B + (size_t)v*VSB + (size_t)zn*BZS + (size_t)yn*BYS;
#pragma unroll
    for (int k2 = 0; k2 < 8; ++k2)                   // x = t+16*k2 < 128, coalesced
        dst[t + 16*k2] = r[BREV(k2)];
}

// P6: inverse FFT along y on packed B (x<128). Read all 256 y, write y<128. In-place.
__global__ void __launch_bounds__(256) k_p6(vf2* __restrict__ B){
    int bid = blockIdx.x;                            // v*1024 + zn*8 + xb
    int xb = bid & 7, zn = (bid >> 3) & 127, v = bid >> 10;
    fft_strided<1,256,128>(B + (size_t)v*VSB + (size_t)zn*BZS + xb*16, BYS);
}

// P7: inverse FFT along z for y<128, x<128 on packed B. Read zn<128,
// output real part of z<128 scaled by 1/256^3 into d_out.
__global__ void __launch_bounds__(256) k_p7(const vf2* __restrict__ B, float* __restrict__ out){
    __shared__ vf2 sh8[8*LSTR];
    __shared__ vf2 tw[256];
    int bid = blockIdx.x;                            // v*1024 + y*8 + xb
    int xb = bid & 7, y = (bid >> 3) & 127, v = bid >> 10;
    const vf2* g = B + (size_t)v*VSB + (size_t)y*BYS + xb*16;
    int t = threadIdx.x >> 4, l = threadIdx.x & 15;
    vf2 r[16];
    vf2 zero; zero.x = 0.f; zero.y = 0.f;
#pragma unroll
    for (int n1 = 0; n1 < 16; ++n1)
        r[n1] = (n1 < 8) ? g[(size_t)(16*n1 + t)*BZS + l] : zero;
    init_tw(tw, 1.f);
    __syncthreads();
    mid256s<1>(r, sh8, tw, t, l);
    const float sc = 1.0f/16777216.0f;               // 1/256^3
    float* dst = out + ((size_t)(v*128)*128 + y)*128 + xb*16 + l;
#pragma unroll
    for (int k2 = 0; k2 < 8; ++k2)                   // k = t + 16*k2 < 128
        dst[(size_t)(t + 16*k2)*16384] = r[BREV(k2)].x * sc;
}

extern "C" void kernel_launch(void* const* d_in, const int* in_sizes, int n_in,
                              void* d_out, int out_size, void* d_ws, size_t ws_size,
                              hipStream_t stream){
    const float* in = (const float*)d_in[0];
    float* out = (float*)d_out;
    vf2* A = (vf2*)d_ws;                   // 134 MB
    vf2* B = A + 2*VS;                     // 67 MB packed
    k_p1 <<< 2048, 256, 0, stream>>>(in, A);
    k_p2 <<< 4096, 256, 0, stream>>>(A);
    k_p3 <<< 8192, 256, 0, stream>>>(A);
    k_p45<<< 4096, 256, 0, stream>>>(A, B);
    k_p6 <<< 2048, 256, 0, stream>>>(B);
    k_p7 <<< 2048, 256, 0, stream>>>(B, out);
}

// Round 10
// 203.336 us; speedup vs baseline: 1.0943x; 1.0943x over previous
//
#include <hip/hip_runtime.h>

// Geometry: M=N=128, padded S=256. Two volumes (b*d=2).
// A: [v][z<128][y:256][x:256] complex fp32 = 134 MB total.
// B (packed): [v][z<128][y:256][x<128] complex fp32 = 67 MB total.
// Forward pass order: x-FFT -> z-FFT (y still <128: half traffic) -> y-FFT.
static constexpr size_t VS   = 8388608;  // 128*256*256 per volume (A)
static constexpr int    ZSTR = 65536;    // 256*256
static constexpr int    YSTR = 256;
static constexpr size_t VSB  = 4194304;  // 128*256*128 per volume (B)
static constexpr int    BZS  = 32768;    // 256*128
static constexpr int    BYS  = 128;
static constexpr int    LSTR = 261;      // LDS line stride (vf2); 5*l mod 16 spreads bank-pairs

typedef float vf2 __attribute__((ext_vector_type(2)));  // complex: .x=re, .y=im -> v_pk_* f32

__device__ __forceinline__ vf2 cmul(vf2 a, vf2 b){
    vf2 asw; asw.x = -a.y; asw.y = a.x;       // i*a
    return a*b.x + asw*b.y;                   // pk_mul + pk_fma
}

constexpr int BREV(int k){ return ((k&1)<<3)|((k&2)<<1)|((k&4)>>1)|((k&8)>>3); }

// Butterfly: a' = a+b; b' = (a-b) rotated by (c,s). Packed VOP3P.
__device__ __forceinline__ void bf(vf2& a, vf2& b, float c, float s){
    vf2 sum = a + b;
    vf2 dif = a - b;
    vf2 dsw; dsw.x = -dif.y; dsw.y = dif.x;   // i*dif
    b = dif*c + dsw*s;
    a = sum;
}

// Fully-unrolled 16-pt DIF FFT, natural input, bit-reversed output: X[k] = r[BREV(k)].
template<int DIR>
__device__ __forceinline__ void fft16(vf2 r[16]){
    constexpr float D = (float)DIR;
    constexpr float C16[8] = {1.f, 0.92387953f, 0.70710678f, 0.38268343f, 0.f, -0.38268343f, -0.70710678f, -0.92387953f};
    constexpr float S16[8] = {0.f, 0.38268343f, 0.70710678f, 0.92387953f, 1.f, 0.92387953f, 0.70710678f, 0.38268343f};
#pragma unroll
    for (int j = 0; j < 8; ++j) bf(r[j], r[j+8], C16[j], D*S16[j]);
    constexpr float C8[4] = {1.f, 0.70710678f, 0.f, -0.70710678f};
    constexpr float S8[4] = {0.f, 0.70710678f, 1.f, 0.70710678f};
#pragma unroll
    for (int g = 0; g < 16; g += 8)
#pragma unroll
        for (int j = 0; j < 4; ++j) bf(r[g+j], r[g+j+4], C8[j], D*S8[j]);
#pragma unroll
    for (int g = 0; g < 16; g += 4){
        bf(r[g],   r[g+2], 1.f, 0.f);
        bf(r[g+1], r[g+3], 0.f, D);
    }
#pragma unroll
    for (int g = 0; g < 16; g += 2) bf(r[g], r[g+1], 1.f, 0.f);
}

// Per-block twiddle table: tw[a*16+b] = e^{DIR*2pi*i*a*b/256}.
// Caller must barrier between init and first use.
__device__ __forceinline__ void init_tw(vf2* tw, float dir){
    int tid = threadIdx.x;
    float ang = dir * 0.0245436926f * (float)((tid >> 4)*(tid & 15));
    float s, c; __sincosf(ang, &s, &c);
    vf2 w; w.x = c; w.y = s;
    tw[tid] = w;
}

// Middle of four-step 256-pt FFT with an 8-LINE transpose buffer (two passes,
// low-l half then high-l half) -> halves LDS -> 8 blocks/CU.
// On entry r[n1] = x[16*n1 + t] for line l; on exit r[BREV(k2)] = X[t + 16*k2].
template<int DIR>
__device__ __forceinline__ void mid256s(vf2 r[16], vf2* sh8, const vf2* tw, int t, int l){
    fft16<DIR>(r);
#pragma unroll
    for (int k1 = 1; k1 < 16; ++k1)
        r[BREV(k1)] = cmul(r[BREV(k1)], tw[k1*16 + t]);   // broadcast across l
    int lr = l & 7;
    bool lo = (l < 8);
    __syncthreads();                      // also protects caller's prior sh8 reads
    if (lo){
#pragma unroll
        for (int k1 = 0; k1 < 16; ++k1) sh8[lr*LSTR + k1*16 + (t ^ k1)] = r[BREV(k1)];
    }
    __syncthreads();
    if (lo){
#pragma unroll
        for (int n2 = 0; n2 < 16; ++n2) r[n2] = sh8[lr*LSTR + t*16 + (n2 ^ t)];
    }
    __syncthreads();
    if (!lo){
#pragma unroll
        for (int k1 = 0; k1 < 16; ++k1) sh8[lr*LSTR + k1*16 + (t ^ k1)] = r[BREV(k1)];
    }
    __syncthreads();
    if (!lo){
#pragma unroll
        for (int n2 = 0; n2 < 16; ++n2) r[n2] = sh8[lr*LSTR + t*16 + (n2 ^ t)];
    }
    fft16<DIR>(r);
}

// Strided-axis FFT: 16 consecutive x per block, stride S elements.
// Reads only idx<NIN (rest structurally zero), writes only idx<NOUT.
template<int DIR, int NIN, int NOUT>
__device__ __forceinline__ void fft_strided(vf2* g, int S){
    __shared__ vf2 sh8[8*LSTR];
    __shared__ vf2 tw[256];
    int t = threadIdx.x >> 4, l = threadIdx.x & 15;
    vf2 r[16];
    vf2 zero; zero.x = 0.f; zero.y = 0.f;
#pragma unroll
    for (int n1 = 0; n1 < 16; ++n1)
        r[n1] = (n1 < NIN/16) ? g[(size_t)(16*n1 + t)*S + l] : zero;   // loads issue first
    init_tw(tw, (float)DIR);
    __syncthreads();                                 // tw ready
    mid256s<DIR>(r, sh8, tw, t, l);
#pragma unroll
    for (int k2 = 0; k2 < 16; ++k2)
        if (k2 < NOUT/16) g[(size_t)(t + 16*k2)*S + l] = r[BREV(k2)];
}

// P1: read input, val = sqrt(relu(f*gz^2)), zero-pad 128->256, forward FFT along x,
// then the exact half-pixel x-average epilogue (two half-passes):
//   avg[k] = 0.5*(X[k] + X[(k-1)&255]), prev tap DROPPED at k=128.
__global__ void __launch_bounds__(256) k_p1(const float* __restrict__ in, vf2* __restrict__ A){
    __shared__ vf2 sh8[8*LSTR];
    __shared__ vf2 tw[256];
    __shared__ float shin[16*130];
    init_tw(tw, -1.f);
    int th = threadIdx.x, bid = blockIdx.x;          // v*1024 + z*8 + yc
    int yc = bid & 7, z = (bid >> 3) & 127, v = bid >> 10;
    float gz = z * (1.0f/127.0f);
    float g2 = gz*gz;
    const float* src = in + (((size_t)(v*128 + z))*128 + yc*16)*128;
    for (int idx = th; idx < 2048; idx += 256){
        float val = src[idx] * g2;
        shin[(idx >> 7)*130 + (idx & 127)] = val > 0.f ? sqrtf(val) : 0.f;
    }
    __syncthreads();
    int t = th >> 4, l = th & 15;
    vf2 r[16];
    vf2 zero; zero.x = 0.f; zero.y = 0.f;
#pragma unroll
    for (int n1 = 0; n1 < 16; ++n1){
        r[n1] = zero;
        if (n1 < 8) r[n1].x = shin[l*130 + 16*n1 + t];
    }
    mid256s<-1>(r, sh8, tw, t, l);
    int lr = l & 7;
    vf2* dst = A + (size_t)v*VS + (size_t)z*ZSTR + (size_t)(yc*16)*YSTR;
#pragma unroll
    for (int half = 0; half < 2; ++half){
        __syncthreads();
        if ((l >> 3) == half){
#pragma unroll
            for (int k2 = 0; k2 < 16; ++k2) sh8[lr*LSTR + t + 16*k2] = r[BREV(k2)];
        }
        __syncthreads();
        vf2* d2 = dst + half*8*YSTR;                 // rows half*8..half*8+8 contiguous
        for (int idx = th; idx < 2048; idx += 256){
            int line = idx >> 8, k = idx & 255;
            vf2 a = sh8[line*LSTR + k];
            vf2 p = sh8[line*LSTR + ((k - 1) & 255)];
            if (k == 128) p = zero;
            d2[idx] = (a + p)*0.5f;
        }
    }
}

// P2z: forward FFT along z — runs BEFORE the y-FFT so only y<128 columns exist:
// half the traffic of the old ordering. Read z<128, write z<128. In-place.
__global__ void __launch_bounds__(256) k_p2z(vf2* __restrict__ A){
    int bid = blockIdx.x;                            // v*2048 + y*16 + xb   (y < 128)
    int xb = bid & 15, y = (bid >> 4) & 127, v = bid >> 11;
    fft_strided<-1,128,128>(A + (size_t)v*VS + (size_t)y*YSTR + xb*16, ZSTR);
}

// P3y: forward FFT along y for each z<128 slab (read y<128, write 256), then the
// exact half-pixel y-average epilogue (split passes through sh8).
__global__ void __launch_bounds__(256) k_p3y(vf2* __restrict__ A){
    __shared__ vf2 sh8[8*LSTR];
    __shared__ vf2 tw[256];
    int bid = blockIdx.x;                            // v*2048 + z*16 + xb   (z < 128)
    int xb = bid & 15, z = (bid >> 4) & 127, v = bid >> 11;
    vf2* g = A + (size_t)v*VS + (size_t)z*ZSTR + xb*16;
    int t = threadIdx.x >> 4, l = threadIdx.x & 15;
    vf2 r[16];
    vf2 zero; zero.x = 0.f; zero.y = 0.f;
#pragma unroll
    for (int n1 = 0; n1 < 16; ++n1)
        r[n1] = (n1 < 8) ? g[(size_t)(16*n1 + t)*YSTR + l] : zero;
    init_tw(tw, -1.f);
    __syncthreads();
    mid256s<-1>(r, sh8, tw, t, l);
    int lr = l & 7;
#pragma unroll
    for (int half = 0; half < 2; ++half){
        __syncthreads();
        if ((l >> 3) == half){
#pragma unroll
            for (int k2 = 0; k2 < 16; ++k2) sh8[lr*LSTR + t + 16*k2] = r[BREV(k2)];
        }
        __syncthreads();
        if ((l >> 3) == half){
#pragma unroll
            for (int k2 = 0; k2 < 16; ++k2){
                int k = t + 16*k2;
                vf2 a = sh8[lr*LSTR + k];
                vf2 p = sh8[lr*LSTR + ((k - 1) & 255)];
                if (k == 128) p = zero;
                g[(size_t)k*YSTR + l] = (a + p)*0.5f;
            }
        }
    }
}

// P45: fused Stolt z-resample (2 taps — x/y averaging baked into A) + x-iFFT.
// Direct global->register gather (roles t=tid&15 lane-fast for coalescing) and
// direct register->global store — no staging LDS, full load MLP.
__global__ void __launch_bounds__(256) k_p45(const vf2* __restrict__ A, vf2* __restrict__ B){
    __shared__ vf2 sh8[8*LSTR];
    __shared__ vf2 tw[256];
    init_tw(tw, 1.f);
    int tid = threadIdx.x, bid = blockIdx.x;         // v*2048 + zn*16 + yc
    int yc = bid & 15, zn = (bid >> 4) & 127, v = bid >> 11;
    const vf2* Av = A + (size_t)v*VS;
    int t = tid & 15, l = tid >> 4;                  // lanes 0..15 = consecutive x
    int yn = yc*16 + l;
    float gy = (yn < 128 ? yn : yn - 256) * (1.0f/128.0f);
    float gz = zn * (1.0f/128.0f);
    float c2 = 0.1024f*gy*gy + gz*gz;
    unsigned rowoff = (unsigned)yn*YSTR;
    vf2 r[16];
#pragma unroll
    for (int n1 = 0; n1 < 16; ++n1){
        int xn = 16*n1 + t;
        float gx = (xn < 128 ? xn : xn - 256) * (1.0f/128.0f);
        float s2 = c2 + 0.1024f*gx*gx;
        float rs = __builtin_amdgcn_rsqf(s2 + 1e-12f);   // 1/gznew; zn==0 row -> wf=0
        float gznew = s2 * rs;
        float pz = gznew*128.0f + 127.5f;
        int zi = (int)pz;                                // trunc == floor (pz>0)
        float dz = pz - (float)zi;
        int zp0 = zi - 128;                              // natural z of first tap
        float wf = gz * rs;                              // gz/gznew
        float w0 = (((unsigned)zp0     < 128u) ? (1.0f - dz) : 0.f) * wf;
        float w1 = (((unsigned)(zp0+1) < 128u) ? dz : 0.f) * wf;
        vf2 v0 = Av[(size_t)((unsigned)(zp0 & 127) * ZSTR) + rowoff + xn];
        vf2 v1 = Av[(size_t)((unsigned)((zp0 + 1) & 127) * ZSTR) + rowoff + xn];
        r[n1] = v0*w0 + v1*w1;
    }
    __syncthreads();                                 // tw ready
    mid256s<1>(r, sh8, tw, t, l);
    vf2* dst = B + (size_t)v*VSB + (size_t)zn*BZS + (size_t)yn*BYS;
#pragma unroll
    for (int k2 = 0; k2 < 8; ++k2)                   // x = t+16*k2 < 128, coalesced
        dst[t + 16*k2] = r[BREV(k2)];
}

// P6: inverse FFT along y on packed B (x<128). Read all 256 y, write y<128. In-place.
__global__ void __launch_bounds__(256) k_p6(vf2* __restrict__ B){
    int bid = blockIdx.x;                            // v*1024 + zn*8 + xb
    int xb = bid & 7, zn = (bid >> 3) & 127, v = bid >> 10;
    fft_strided<1,256,128>(B + (size_t)v*VSB + (size_t)zn*BZS + xb*16, BYS);
}

// P7: inverse FFT along z for y<128, x<128 on packed B. Read zn<128,
// output real part of z<128 scaled by 1/256^3 into d_out.
__global__ void __launch_bounds__(256) k_p7(const vf2* __restrict__ B, float* __restrict__ out){
    __shared__ vf2 sh8[8*LSTR];
    __shared__ vf2 tw[256];
    int bid = blockIdx.x;                            // v*1024 + y*8 + xb
    int xb = bid & 7, y = (bid >> 3) & 127, v = bid >> 10;
    const vf2* g = B + (size_t)v*VSB + (size_t)y*BYS + xb*16;
    int t = threadIdx.x >> 4, l = threadIdx.x & 15;
    vf2 r[16];
    vf2 zero; zero.x = 0.f; zero.y = 0.f;
#pragma unroll
    for (int n1 = 0; n1 < 16; ++n1)
        r[n1] = (n1 < 8) ? g[(size_t)(16*n1 + t)*BZS + l] : zero;
    init_tw(tw, 1.f);
    __syncthreads();
    mid256s<1>(r, sh8, tw, t, l);
    const float sc = 1.0f/16777216.0f;               // 1/256^3
    float* dst = out + ((size_t)(v*128)*128 + y)*128 + xb*16 + l;
#pragma unroll
    for (int k2 = 0; k2 < 8; ++k2)                   // k = t + 16*k2 < 128
        dst[(size_t)(t + 16*k2)*16384] = r[BREV(k2)].x * sc;
}

extern "C" void kernel_launch(void* const* d_in, const int* in_sizes, int n_in,
                              void* d_out, int out_size, void* d_ws, size_t ws_size,
                              hipStream_t stream){
    const float* in = (const float*)d_in[0];
    float* out = (float*)d_out;
    vf2* A = (vf2*)d_ws;                   // 134 MB
    vf2* B = A + 2*VS;                     // 67 MB packed
    k_p1 <<< 2048, 256, 0, stream>>>(in, A);
    k_p2z<<< 4096, 256, 0, stream>>>(A);   // z-FFT first: y<128 -> half traffic
    k_p3y<<< 4096, 256, 0, stream>>>(A);
    k_p45<<< 4096, 256, 0, stream>>>(A, B);
    k_p6 <<< 2048, 256, 0, stream>>>(B);
    k_p7 <<< 2048, 256, 0, stream>>>(B, out);
}